// Round 10
// baseline (3866.891 us; speedup 1.0000x reference)
//
#include <hip/hip_runtime.h>

#define SEQ 1024
#define NB  64
#define NI  256
#define NH  256

typedef __bf16 bf16x8 __attribute__((ext_vector_type(8)));
typedef float  f32x4  __attribute__((ext_vector_type(4)));
typedef unsigned int u32x4 __attribute__((ext_vector_type(4)));
typedef unsigned short u16;
typedef unsigned int u32;

static __device__ __forceinline__ u16 f2bf(float f) {
    u32 u = __float_as_uint(f);
    u += 0x7fffu + ((u >> 16) & 1u);
    return (u16)(u >> 16);
}
static __device__ __forceinline__ float sigm_(float x) {
    return __builtin_amdgcn_rcpf(1.0f + __builtin_amdgcn_exp2f(-1.4426950408889634f * x));
}
static __device__ __forceinline__ float tanh_(float x) {
    return 1.0f - 2.0f * __builtin_amdgcn_rcpf(__builtin_amdgcn_exp2f(2.8853900817779268f * x) + 1.0f);
}

// Transposed MFMA: A = weight^T from AGPR, B = data from VGPR.
// D[h][batch] += W^T[h][k] * data^T[k][batch]
static __device__ __forceinline__ void mfma_wd(f32x4& c, bf16x8 w, bf16x8 d) {
    asm("v_mfma_f32_16x16x32_bf16 %0, %1, %2, %0" : "+v"(c) : "a"(w), "v"(d));
}

static __device__ __forceinline__ void st_mall_u32(u32* p, u32 v) {
    asm volatile("global_store_dword %0, %1, off sc0 sc1" :: "v"(p), "v"(v) : "memory");
}

static __device__ __forceinline__ bf16x8 asbf(u32x4 v) {
    union { u32x4 u; bf16x8 b; } c; c.u = v; return c.b;
}

// 8x16B x-row prefetch (issue only; drained by a later vmcnt(0))
#define PREFETCH8(dst, p)                                                    \
    asm volatile(                                                            \
        "global_load_dwordx4 %0, %8, off\n\t"                                \
        "global_load_dwordx4 %1, %8, off offset:16\n\t"                      \
        "global_load_dwordx4 %2, %8, off offset:32\n\t"                      \
        "global_load_dwordx4 %3, %8, off offset:48\n\t"                      \
        "global_load_dwordx4 %4, %8, off offset:64\n\t"                      \
        "global_load_dwordx4 %5, %8, off offset:80\n\t"                      \
        "global_load_dwordx4 %6, %8, off offset:96\n\t"                      \
        "global_load_dwordx4 %7, %8, off offset:112"                         \
        : "=&v"(dst[0]), "=&v"(dst[1]), "=&v"(dst[2]), "=&v"(dst[3]),        \
          "=&v"(dst[4]), "=&v"(dst[5]), "=&v"(dst[6]), "=&v"(dst[7])         \
        : "v"(p) : "memory")

// Issue 16 B-fragment loads (2 row-tiles x 8 k-slices) from mex. The polled
// data IS the MFMA B operand — no LDS staging, no transpose barrier.
#define ISSUE16(MP) do {                                                     \
    asm volatile(                                                            \
        "global_load_dwordx4 %0, %8, off sc0 sc1\n\t"                        \
        "global_load_dwordx4 %1, %8, off offset:64 sc0 sc1\n\t"              \
        "global_load_dwordx4 %2, %8, off offset:128 sc0 sc1\n\t"             \
        "global_load_dwordx4 %3, %8, off offset:192 sc0 sc1\n\t"             \
        "global_load_dwordx4 %4, %8, off offset:256 sc0 sc1\n\t"             \
        "global_load_dwordx4 %5, %8, off offset:320 sc0 sc1\n\t"             \
        "global_load_dwordx4 %6, %8, off offset:384 sc0 sc1\n\t"             \
        "global_load_dwordx4 %7, %8, off offset:448 sc0 sc1"                 \
        : "=&v"(mwv[0]), "=&v"(mwv[1]), "=&v"(mwv[2]), "=&v"(mwv[3]),        \
          "=&v"(mwv[4]), "=&v"(mwv[5]), "=&v"(mwv[6]), "=&v"(mwv[7])         \
        : "v"(MP) : "memory");                                               \
    asm volatile(                                                            \
        "global_load_dwordx4 %0, %8, off sc0 sc1\n\t"                        \
        "global_load_dwordx4 %1, %8, off offset:64 sc0 sc1\n\t"              \
        "global_load_dwordx4 %2, %8, off offset:128 sc0 sc1\n\t"             \
        "global_load_dwordx4 %3, %8, off offset:192 sc0 sc1\n\t"             \
        "global_load_dwordx4 %4, %8, off offset:256 sc0 sc1\n\t"             \
        "global_load_dwordx4 %5, %8, off offset:320 sc0 sc1\n\t"             \
        "global_load_dwordx4 %6, %8, off offset:384 sc0 sc1\n\t"             \
        "global_load_dwordx4 %7, %8, off offset:448 sc0 sc1"                 \
        : "=&v"(mwv[8]),  "=&v"(mwv[9]),  "=&v"(mwv[10]), "=&v"(mwv[11]),    \
          "=&v"(mwv[12]), "=&v"(mwv[13]), "=&v"(mwv[14]), "=&v"(mwv[15])     \
        : "v"((MP) + 2048) : "memory");                                      \
} while (0)

#define VMWAIT() do {                                                        \
    asm volatile("s_waitcnt vmcnt(0)" ::: "memory");                         \
    __builtin_amdgcn_sched_barrier(0); } while (0)

#define BAR_LGKM() do {                                                      \
    asm volatile("s_waitcnt lgkmcnt(0)" ::: "memory");                       \
    __builtin_amdgcn_s_barrier();                                            \
    __builtin_amdgcn_sched_barrier(0); } while (0)

// ctl (u32): [0..1] leader | [2..3] ticket  (re-zeroed every launch).
// mex (u32, ws+4KB): [parity*2+g][32 rows(batch)][128 u32(k)], word = 2 bf16,
// bit14 of each bf16 = step-parity tag ((step>>1)&1). |m|<2 => bit14 free.
__global__ __launch_bounds__(256, 1) __attribute__((amdgpu_waves_per_eu(1, 1)))
void nas_scan(const float* __restrict__ xg, const float* __restrict__ wih,
              const float* __restrict__ whh, float* __restrict__ out,
              u32* ctl, u32* mex)
{
    __shared__ __align__(16) unsigned char xbuf[32 * 512]; // x[s] bf16, swizzled
    __shared__ float gbuf[32 * 133];                       // [batch][gate*16+h]
    __shared__ int sh_group, sh_role;

    const int t    = threadIdx.x;
    const int lane = t & 63;
    const int wave = t >> 6;

    // ---- self-organizing XCD-co-located claim (proven: FETCH 413->54MB) ----
    if (t == 0) {
        u32 xcc;
        asm volatile("s_getreg_b32 %0, hwreg(HW_REG_XCC_ID)" : "=s"(xcc));
        int grp = -1, rl = -1;
        for (int gq = 0; gq < 2 && grp < 0; ++gq) {
            u32 exp = 0u;
            bool won = __hip_atomic_compare_exchange_strong(
                &ctl[gq], &exp, xcc + 1u,
                __ATOMIC_ACQ_REL, __ATOMIC_ACQUIRE, __HIP_MEMORY_SCOPE_AGENT);
            u32 ldr = won ? (xcc + 1u) : exp;
            if (ldr == xcc + 1u) {
                u32 r = __hip_atomic_fetch_add(&ctl[2 + gq], 1u,
                                               __ATOMIC_RELAXED, __HIP_MEMORY_SCOPE_AGENT);
                if (r < 16u) { grp = gq; rl = (int)r; }
            }
        }
        sh_group = grp; sh_role = rl;
    }
    __syncthreads();
    const int g = sh_group;
    if (g < 0) return;
    const int role = sh_role;
    const int c0   = role * 16;

    const int fr = lane & 15;   // transposed: batch-within-tile (B-col) / h (A-row)
    const int fq = lane >> 4;   // k-window index

    // ---- weight A^T-fragments -> AGPRs, pinned. A-row mapping == old B-col
    // mapping, so the load indexing is IDENTICAL to rounds 4-9. ----
    bf16x8 wfih[2][8], wfhh[2][8];
#pragma unroll
    for (int gi = 0; gi < 2; ++gi) {
        const int gg = wave * 2 + gi;
#pragma unroll
        for (int ks = 0; ks < 8; ++ks) {
            bf16x8 a, b;
#pragma unroll
            for (int j = 0; j < 8; ++j) {
                const int idx = (gg * NH + ks * 32 + fq * 8 + j) * NH + (c0 + fr);
                a[j] = (__bf16)wih[idx];
                b[j] = (__bf16)whh[idx];
            }
            wfih[gi][ks] = a;
            wfhh[gi][ks] = b;
        }
    }
#pragma unroll
    for (int gi = 0; gi < 2; ++gi)
#pragma unroll
        for (int ks = 0; ks < 8; ++ks)
            asm volatile("" : "+a"(wfih[gi][ks]), "+a"(wfhh[gi][ks]));

    // ---- x addressing: thread -> batch row t>>3, cols (t&7)*32..+31 ----
    const int xr  = t >> 3;
    const int xcb = (t & 7) * 32;
    const float* xbase = xg + (size_t)(g * 32 + xr) * NI + xcb;
    const unsigned sbase = (unsigned)xr * 512u + (unsigned)xcb * 2u;
    const unsigned sswz  = ((unsigned)xr & 7u) << 4;

    f32x4 xpA[8], xpB[8];
#pragma unroll
    for (int i = 0; i < 8; ++i) xpA[i] = *(const f32x4*)(xbase + i * 4);
    {
        u32 w[16];
#pragma unroll
        for (int jj = 0; jj < 16; ++jj) {
            const float a = xpA[jj >> 1][(jj & 1) * 2 + 0];
            const float b = xpA[jj >> 1][(jj & 1) * 2 + 1];
            w[jj] = (u32)f2bf(a) | ((u32)f2bf(b) << 16);
        }
#pragma unroll
        for (int q = 0; q < 4; ++q) {
            u32x4 W = {w[q * 4 + 0], w[q * 4 + 1], w[q * 4 + 2], w[q * 4 + 3]};
            *(u32x4*)(xbuf + ((sbase + (unsigned)q * 16u) ^ sswz)) = W;
        }
    }
    __syncthreads();

    // x B-frag reads: row = batch = fr (tile0) / 16+fr (tile1) — unchanged.
    const unsigned aswz = ((unsigned)fr & 7u) << 4;
    const unsigned ab0  = (unsigned)fr * 512u + (unsigned)fq * 16u;
    const unsigned ab1  = ab0 + 16u * 512u;

    const f32x4 fzero = {0.f, 0.f, 0.f, 0.f};
    f32x4 accx[2][2];
#pragma unroll
    for (int m = 0; m < 2; ++m)
#pragma unroll
        for (int gi = 0; gi < 2; ++gi) accx[m][gi] = fzero;
#pragma unroll
    for (int ks = 0; ks < 8; ++ks) {
        bf16x8 a0 = *(const bf16x8*)(xbuf + ((ab0 + (unsigned)ks * 64u) ^ aswz));
        bf16x8 a1 = *(const bf16x8*)(xbuf + ((ab1 + (unsigned)ks * 64u) ^ aswz));
#pragma unroll
        for (int gi = 0; gi < 2; ++gi) {
            mfma_wd(accx[0][gi], wfih[gi][ks], a0);
            mfma_wd(accx[1][gi], wfih[gi][ks], a1);
        }
    }
#pragma unroll
    for (int i = 0; i < 8; ++i) xpA[i] = *(const f32x4*)(xbase + (size_t)(NB * NI) + i * 4);

    const int r_own = t >> 3;
    const int cp    = t & 7;
    float cA = 0.0f, cB = 0.0f;

    u32x4 mwv[16];   // in-flight m B-frags (issued at end of previous step)

#define STEP(S_, XPC, XPN) do {                                               \
    const int s = (S_);                                                       \
    f32x4 acc[2][2];                                                          \
    _Pragma("unroll")                                                         \
    for (int m = 0; m < 2; ++m)                                               \
        _Pragma("unroll")                                                     \
        for (int gi = 0; gi < 2; ++gi) acc[m][gi] = accx[m][gi];              \
    if (s > 0) {                                                              \
        const u32 txor = (s & 2) ? 0x40004000u : 0u;                          \
        const u32* mp = mex + (size_t)((s & 1) * 2 + g) * 4096                \
                      + (size_t)(fr * 128 + fq * 4);                          \
        for (;;) {                                                            \
            VMWAIT();                                                         \
            u32 badw = 0u;                                                    \
            _Pragma("unroll")                                                 \
            for (int i = 0; i < 16; ++i)                                      \
                badw |= (mwv[i][0] ^ txor) | (mwv[i][1] ^ txor)               \
                      | (mwv[i][2] ^ txor) | (mwv[i][3] ^ txor);              \
            if (__all((int)((badw & 0x40004000u) == 0u))) break;              \
            ISSUE16(mp);                                                      \
        }                                                                     \
        if (s & 2) {   /* tag bit set this parity: clear before MFMA */       \
            _Pragma("unroll")                                                 \
            for (int i = 0; i < 16; ++i) {                                    \
                mwv[i][0] &= 0xBFFFBFFFu; mwv[i][1] &= 0xBFFFBFFFu;           \
                mwv[i][2] &= 0xBFFFBFFFu; mwv[i][3] &= 0xBFFFBFFFu;           \
            }                                                                 \
        }                                                                     \
        {   /* prefetch x[s+2] */                                             \
            const int sp = (s + 2 < SEQ) ? s + 2 : s;                         \
            const float* xq = xbase + (size_t)sp * (NB * NI);                 \
            PREFETCH8(XPN, xq);                                               \
        }                                                                     \
        _Pragma("unroll")                                                     \
        for (int ks = 0; ks < 8; ++ks) {                                      \
            const bf16x8 b0 = asbf(mwv[ks]);                                  \
            const bf16x8 b1 = asbf(mwv[8 + ks]);                              \
            _Pragma("unroll")                                                 \
            for (int gi = 0; gi < 2; ++gi) {                                  \
                mfma_wd(acc[0][gi], wfhh[gi][ks], b0);                        \
                mfma_wd(acc[1][gi], wfhh[gi][ks], b1);                        \
            }                                                                 \
        }                                                                     \
    } else {                                                                  \
        const float* xq = xbase + (size_t)2 * (NB * NI);                      \
        PREFETCH8(XPN, xq);                                                   \
    }                                                                         \
    /* gates -> gbuf. Transposed C-frag: row(h) = fq*4+j, col(batch) = fr. */ \
    _Pragma("unroll")                                                         \
    for (int m = 0; m < 2; ++m)                                               \
        _Pragma("unroll")                                                     \
        for (int gi = 0; gi < 2; ++gi) {                                      \
            const int rowb = m * 16 + fr;                                     \
            const int colh = (wave * 2 + gi) * 16 + fq * 4;                   \
            _Pragma("unroll")                                                 \
            for (int j = 0; j < 4; ++j)                                       \
                gbuf[rowb * 133 + colh + j] = acc[m][gi][j];                  \
        }                                                                     \
    BAR_LGKM();                                                               \
    float nm0, nm1;                                                           \
    {                                                                         \
        float nc[2], nm[2];                                                   \
        const float* gb = gbuf + r_own * 133 + cp * 2;                        \
        _Pragma("unroll")                                                     \
        for (int e = 0; e < 2; ++e) {                                         \
            const float q0 = gb[0 * 16 + e], q1 = gb[1 * 16 + e];             \
            const float q2 = gb[2 * 16 + e], q3 = gb[3 * 16 + e];             \
            const float q4 = gb[4 * 16 + e], q5 = gb[5 * 16 + e];             \
            const float q6 = gb[6 * 16 + e], q7 = gb[7 * 16 + e];             \
            const float l10 = sigm_(q0);                                      \
            const float l11 = fmaxf(q1, 0.0f);                                \
            const float l12 = sigm_(q2);                                      \
            const float l13 = fmaxf(q3, 0.0f);                                \
            const float l14 = tanh_(q4);                                      \
            const float l15 = sigm_(q5);                                      \
            const float l16 = tanh_(q6);                                      \
            const float l17 = sigm_(q7);                                      \
            const float l20 = tanh_(l10 * l11);                               \
            const float l21 = tanh_(l12 + l13);                               \
            const float l22 = tanh_(l14 * l15);                               \
            const float l23 = sigm_(l16 + l17);                               \
            const float cold = (e == 0) ? cA : cB;                            \
            const float l20v = tanh_(l20 + cold);                             \
            const float ncv  = l20v * l21;                                    \
            const float l31  = tanh_(l22 + l23);                              \
            nc[e] = ncv;                                                      \
            nm[e] = tanh_(ncv * l31);                                         \
        }                                                                     \
        cA = nc[0]; cB = nc[1];                                               \
        nm0 = nm[0]; nm1 = nm[1];                                             \
    }                                                                         \
    if (s == SEQ - 1) {                                                       \
        const int obase = (g * 32 + r_own) * NH + c0 + cp * 2;                \
        out[obase + 0] = cA + nm0;                                            \
        out[obase + 1] = cB + nm1;                                            \
    } else {                                                                  \
        /* fire-and-forget tagged publish (r9-proven) */                      \
        const u32 tb = ((u32)(s + 1) & 2u) << 13;                             \
        u32* mw = mex + (size_t)(((s + 1) & 1) * 2 + g) * 4096                \
                      + (size_t)(r_own * 128 + role * 8 + cp);                \
        const u32 pk = ((u32)f2bf(nm0) | tb)                                  \
                     | ((((u32)f2bf(nm1)) | tb) << 16);                       \
        st_mall_u32(mw, pk);                                                  \
        {   /* stage x[s+1] */                                                \
            u32 w[16];                                                        \
            _Pragma("unroll")                                                 \
            for (int jj = 0; jj < 16; ++jj) {                                 \
                const float a = XPC[jj >> 1][(jj & 1) * 2 + 0];               \
                const float b = XPC[jj >> 1][(jj & 1) * 2 + 1];               \
                w[jj] = (u32)f2bf(a) | ((u32)f2bf(b) << 16);                  \
            }                                                                 \
            _Pragma("unroll")                                                 \
            for (int q = 0; q < 4; ++q) {                                     \
                u32x4 W = {w[q * 4 + 0], w[q * 4 + 1], w[q * 4 + 2], w[q * 4 + 3]}; \
                *(u32x4*)(xbuf + ((sbase + (unsigned)q * 16u) ^ sswz)) = W;   \
            }                                                                 \
        }                                                                     \
        BAR_LGKM();                                                           \
        {   /* EARLY-ISSUE next step's m B-frags: RT hides under accx MFMAs */\
            const u32* np = mex + (size_t)(((s + 1) & 1) * 2 + g) * 4096      \
                          + (size_t)(fr * 128 + fq * 4);                      \
            ISSUE16(np);                                                      \
        }                                                                     \
        _Pragma("unroll")                                                     \
        for (int m = 0; m < 2; ++m)                                           \
            _Pragma("unroll")                                                 \
            for (int gi = 0; gi < 2; ++gi) accx[m][gi] = fzero;               \
        _Pragma("unroll")                                                     \
        for (int ks = 0; ks < 8; ++ks) {                                      \
            bf16x8 a0 = *(const bf16x8*)(xbuf + ((ab0 + (unsigned)ks * 64u) ^ aswz)); \
            bf16x8 a1 = *(const bf16x8*)(xbuf + ((ab1 + (unsigned)ks * 64u) ^ aswz)); \
            _Pragma("unroll")                                                 \
            for (int gi = 0; gi < 2; ++gi) {                                  \
                mfma_wd(accx[0][gi], wfih[gi][ks], a0);                       \
                mfma_wd(accx[1][gi], wfih[gi][ks], a1);                       \
            }                                                                 \
        }                                                                     \
    }                                                                         \
} while (0)

    for (int sb = 0; sb < SEQ; sb += 2) {
        STEP(sb,     xpA, xpB);
        STEP(sb + 1, xpB, xpA);
    }
#undef STEP
}

// Per-launch re-init: parity-0 buffer -> tag0 words, parity-1 -> tag1 words,
// so the first poll of each buffer mismatches its expected tag.
__global__ void nas_init(u32* ctl, u32* mex) {
    const int b = blockIdx.x, t = threadIdx.x;
    if (b < 16) {
        const u32 v = (b < 8) ? 0u : 0x40004000u;
        u32x4 vv = {v, v, v, v};
        u32* p = mex + (size_t)b * 1024 + (size_t)t * 4;
        asm volatile("global_store_dwordx4 %0, %1, off sc0 sc1" :: "v"(p), "v"(vv) : "memory");
    } else if (t < 16) {
        u32* p = ctl + t;
        asm volatile("global_store_dword %0, %1, off sc0 sc1" :: "v"(p), "v"(0u) : "memory");
    }
}

extern "C" void kernel_launch(void* const* d_in, const int* in_sizes, int n_in,
                              void* d_out, int out_size, void* d_ws, size_t ws_size,
                              hipStream_t stream) {
    (void)in_sizes; (void)n_in; (void)out_size; (void)ws_size;
    const float* x   = (const float*)d_in[0];
    const float* wih = (const float*)d_in[1];
    const float* whh = (const float*)d_in[2];
    float* out = (float*)d_out;

    u32* ctl = (u32*)d_ws;                    // claim vars
    u32* mex = (u32*)((char*)d_ws + 4096);    // 64 KB tagged m exchange

    nas_init<<<dim3(17), dim3(256), 0, stream>>>(ctl, mex);
    nas_scan<<<dim3(256), dim3(256), 0, stream>>>(x, wih, whh, out, ctl, mex);
}

// Round 15
// 2604.992 us; speedup vs baseline: 1.4844x; 1.4844x over previous
//
#include <hip/hip_runtime.h>

#define SEQ 1024
#define NB  64
#define NI  256
#define NH  256

typedef __bf16 bf16x8 __attribute__((ext_vector_type(8)));
typedef float  f32x4  __attribute__((ext_vector_type(4)));
typedef unsigned int u32x4 __attribute__((ext_vector_type(4)));
typedef unsigned short u16;
typedef unsigned int u32;

static __device__ __forceinline__ u16 f2bf(float f) {
    u32 u = __float_as_uint(f);
    u += 0x7fffu + ((u >> 16) & 1u);
    return (u16)(u >> 16);
}
static __device__ __forceinline__ float sigm_(float x) {
    return __builtin_amdgcn_rcpf(1.0f + __builtin_amdgcn_exp2f(-1.4426950408889634f * x));
}
static __device__ __forceinline__ float tanh_(float x) {
    return 1.0f - 2.0f * __builtin_amdgcn_rcpf(__builtin_amdgcn_exp2f(2.8853900817779268f * x) + 1.0f);
}

// MFMA with B (weights) in AGPRs — keeps the VGPR file for working state.
static __device__ __forceinline__ void mfma_ab(f32x4& c, bf16x8 a, bf16x8 b) {
    asm("v_mfma_f32_16x16x32_bf16 %0, %1, %2, %0" : "+v"(c) : "v"(a), "a"(b));
}

static __device__ __forceinline__ void st_mall_u32(u32* p, u32 v) {
    asm volatile("global_store_dword %0, %1, off sc0 sc1" :: "v"(p), "v"(v) : "memory");
}

// 8x16B x-row prefetch (issue only)
#define PREFETCH8(dst, p)                                                    \
    asm volatile(                                                            \
        "global_load_dwordx4 %0, %8, off\n\t"                                \
        "global_load_dwordx4 %1, %8, off offset:16\n\t"                      \
        "global_load_dwordx4 %2, %8, off offset:32\n\t"                      \
        "global_load_dwordx4 %3, %8, off offset:48\n\t"                      \
        "global_load_dwordx4 %4, %8, off offset:64\n\t"                      \
        "global_load_dwordx4 %5, %8, off offset:80\n\t"                      \
        "global_load_dwordx4 %6, %8, off offset:96\n\t"                      \
        "global_load_dwordx4 %7, %8, off offset:112"                         \
        : "=&v"(dst[0]), "=&v"(dst[1]), "=&v"(dst[2]), "=&v"(dst[3]),        \
          "=&v"(dst[4]), "=&v"(dst[5]), "=&v"(dst[6]), "=&v"(dst[7])         \
        : "v"(p) : "memory")

#define BAR_LGKM() do {                                                      \
    asm volatile("s_waitcnt lgkmcnt(0)" ::: "memory");                       \
    __builtin_amdgcn_s_barrier();                                            \
    __builtin_amdgcn_sched_barrier(0); } while (0)

// ctl (u32): [0..1] leader | [2..3] ticket  (re-zeroed every launch).
// mex (u32, ws+4KB): [parity][group][32 rows][128 u32], word = 2 packed bf16,
// each with bit14 = step-parity tag ( (step>>1)&1 ). 64 KB total.
__global__ __launch_bounds__(256, 1) __attribute__((amdgpu_waves_per_eu(1, 1)))
void nas_scan(const float* __restrict__ xg, const float* __restrict__ wih,
              const float* __restrict__ whh, float* __restrict__ out,
              u32* ctl, u32* mex)
{
    __shared__ __align__(16) unsigned char xbuf[32 * 512];   // x[s] bf16, swizzled
    __shared__ __align__(16) unsigned char mstage[32 * 512]; // m bf16, swizzled
    __shared__ float gbuf[32 * 133];
    __shared__ int sh_group, sh_role;

    const int t    = threadIdx.x;
    const int lane = t & 63;
    const int wave = t >> 6;

    // ---- self-organizing XCD-co-located claim (proven: FETCH 413->54MB) ----
    if (t == 0) {
        u32 xcc;
        asm volatile("s_getreg_b32 %0, hwreg(HW_REG_XCC_ID)" : "=s"(xcc));
        int grp = -1, rl = -1;
        for (int gq = 0; gq < 2 && grp < 0; ++gq) {
            u32 exp = 0u;
            bool won = __hip_atomic_compare_exchange_strong(
                &ctl[gq], &exp, xcc + 1u,
                __ATOMIC_ACQ_REL, __ATOMIC_ACQUIRE, __HIP_MEMORY_SCOPE_AGENT);
            u32 ldr = won ? (xcc + 1u) : exp;
            if (ldr == xcc + 1u) {
                u32 r = __hip_atomic_fetch_add(&ctl[2 + gq], 1u,
                                               __ATOMIC_RELAXED, __HIP_MEMORY_SCOPE_AGENT);
                if (r < 16u) { grp = gq; rl = (int)r; }
            }
        }
        sh_group = grp; sh_role = rl;
    }
    __syncthreads();
    const int g = sh_group;
    if (g < 0) return;
    const int role = sh_role;
    const int c0   = role * 16;

    const int fr = lane & 15;
    const int fq = lane >> 4;

    // ---- weight B-fragments -> AGPRs, pinned ----
    bf16x8 wfih[2][8], wfhh[2][8];
#pragma unroll
    for (int gi = 0; gi < 2; ++gi) {
        const int gg = wave * 2 + gi;
#pragma unroll
        for (int ks = 0; ks < 8; ++ks) {
            bf16x8 a, b;
#pragma unroll
            for (int j = 0; j < 8; ++j) {
                const int idx = (gg * NH + ks * 32 + fq * 8 + j) * NH + (c0 + fr);
                a[j] = (__bf16)wih[idx];
                b[j] = (__bf16)whh[idx];
            }
            wfih[gi][ks] = a;
            wfhh[gi][ks] = b;
        }
    }
#pragma unroll
    for (int gi = 0; gi < 2; ++gi)
#pragma unroll
        for (int ks = 0; ks < 8; ++ks)
            asm volatile("" : "+a"(wfih[gi][ks]), "+a"(wfhh[gi][ks]));

    // ---- x addressing: thread -> row t>>3, cols (t&7)*32..+31 ----
    const int xr  = t >> 3;
    const int xcb = (t & 7) * 32;
    const float* xbase = xg + (size_t)(g * 32 + xr) * NI + xcb;
    const unsigned sbase = (unsigned)xr * 512u + (unsigned)xcb * 2u;
    const unsigned sswz  = ((unsigned)xr & 7u) << 4;

    f32x4 xpA[8], xpB[8];
#pragma unroll
    for (int i = 0; i < 8; ++i) xpA[i] = *(const f32x4*)(xbase + i * 4);
    {
        u32 w[16];
#pragma unroll
        for (int jj = 0; jj < 16; ++jj) {
            const float a = xpA[jj >> 1][(jj & 1) * 2 + 0];
            const float b = xpA[jj >> 1][(jj & 1) * 2 + 1];
            w[jj] = (u32)f2bf(a) | ((u32)f2bf(b) << 16);
        }
#pragma unroll
        for (int q = 0; q < 4; ++q) {
            u32x4 W = {w[q * 4 + 0], w[q * 4 + 1], w[q * 4 + 2], w[q * 4 + 3]};
            *(u32x4*)(xbuf + ((sbase + (unsigned)q * 16u) ^ sswz)) = W;
        }
    }
    __syncthreads();

    const unsigned aswz = ((unsigned)fr & 7u) << 4;
    const unsigned ab0  = (unsigned)fr * 512u + (unsigned)fq * 16u;
    const unsigned ab1  = ab0 + 16u * 512u;

    const f32x4 fzero = {0.f, 0.f, 0.f, 0.f};
    f32x4 accx[2][2];
#pragma unroll
    for (int m = 0; m < 2; ++m)
#pragma unroll
        for (int gi = 0; gi < 2; ++gi) accx[m][gi] = fzero;
#pragma unroll
    for (int ks = 0; ks < 8; ++ks) {
        bf16x8 a0 = *(const bf16x8*)(xbuf + ((ab0 + (unsigned)ks * 64u) ^ aswz));
        bf16x8 a1 = *(const bf16x8*)(xbuf + ((ab1 + (unsigned)ks * 64u) ^ aswz));
#pragma unroll
        for (int gi = 0; gi < 2; ++gi) {
            mfma_ab(accx[0][gi], a0, wfih[gi][ks]);
            mfma_ab(accx[1][gi], a1, wfih[gi][ks]);
        }
    }
#pragma unroll
    for (int i = 0; i < 8; ++i) xpA[i] = *(const f32x4*)(xbase + (size_t)(NB * NI) + i * 4);

    const int r_own = t >> 3;
    const int cp    = t & 7;
    float cA = 0.0f, cB = 0.0f;

#define STEP(S_, XPC, XPN) do {                                               \
    const int st = (S_);                                                      \
    f32x4 acc[2][2];                                                          \
    _Pragma("unroll")                                                         \
    for (int m = 0; m < 2; ++m)                                               \
        _Pragma("unroll")                                                     \
        for (int gi = 0; gi < 2; ++gi) acc[m][gi] = accx[m][gi];              \
    if (st > 0) {                                                             \
        /* poll own 64B of tagged m directly: data IS the flag */             \
        const u32 txor = (st & 2) ? 0x40004000u : 0u;                         \
        const u32* mp = mex + (size_t)((st & 1) * 2 + g) * 4096 + (size_t)t * 16; \
        u32x4 w0, w1, w2, w3;                                                 \
        for (;;) {                                                            \
            asm volatile(                                                     \
                "global_load_dwordx4 %0, %4, off sc0 sc1\n\t"                 \
                "global_load_dwordx4 %1, %4, off offset:16 sc0 sc1\n\t"       \
                "global_load_dwordx4 %2, %4, off offset:32 sc0 sc1\n\t"       \
                "global_load_dwordx4 %3, %4, off offset:48 sc0 sc1\n\t"       \
                "s_waitcnt vmcnt(0)"                                          \
                : "=&v"(w0), "=&v"(w1), "=&v"(w2), "=&v"(w3)                  \
                : "v"(mp) : "memory");                                        \
            u32 bad = 0u;                                                     \
            _Pragma("unroll")                                                 \
            for (int q = 0; q < 4; ++q) {                                     \
                bad |= (w0[q] ^ txor); bad |= (w1[q] ^ txor);                 \
                bad |= (w2[q] ^ txor); bad |= (w3[q] ^ txor);                 \
            }                                                                 \
            if (__all((int)((bad & 0x40004000u) == 0u))) break;               \
        }                                                                     \
        {   /* prefetch x[st+2] into the spare reg set */                     \
            const int sp = (st + 2 < SEQ) ? st + 2 : st;                      \
            const float* xq = xbase + (size_t)sp * (NB * NI);                 \
            PREFETCH8(XPN, xq);                                               \
        }                                                                     \
        {   /* clear tag bits, stage to swizzled LDS */                       \
            const unsigned mo  = (unsigned)t * 64u;                           \
            const unsigned msw = ((unsigned)(t >> 3) & 7u) << 4;              \
            u32x4 q0 = {w0[0] & 0xBFFFBFFFu, w0[1] & 0xBFFFBFFFu,             \
                        w0[2] & 0xBFFFBFFFu, w0[3] & 0xBFFFBFFFu};            \
            u32x4 q1 = {w1[0] & 0xBFFFBFFFu, w1[1] & 0xBFFFBFFFu,             \
                        w1[2] & 0xBFFFBFFFu, w1[3] & 0xBFFFBFFFu};            \
            u32x4 q2 = {w2[0] & 0xBFFFBFFFu, w2[1] & 0xBFFFBFFFu,             \
                        w2[2] & 0xBFFFBFFFu, w2[3] & 0xBFFFBFFFu};            \
            u32x4 q3 = {w3[0] & 0xBFFFBFFFu, w3[1] & 0xBFFFBFFFu,             \
                        w3[2] & 0xBFFFBFFFu, w3[3] & 0xBFFFBFFFu};            \
            *(u32x4*)(mstage + ((mo + 0u)  ^ msw)) = q0;                      \
            *(u32x4*)(mstage + ((mo + 16u) ^ msw)) = q1;                      \
            *(u32x4*)(mstage + ((mo + 32u) ^ msw)) = q2;                      \
            *(u32x4*)(mstage + ((mo + 48u) ^ msw)) = q3;                      \
        }                                                                     \
        BAR_LGKM();                                                           \
        _Pragma("unroll")                                                     \
        for (int ks = 0; ks < 8; ++ks) {                                      \
            bf16x8 a0 = *(const bf16x8*)(mstage + ((ab0 + (unsigned)ks * 64u) ^ aswz)); \
            bf16x8 a1 = *(const bf16x8*)(mstage + ((ab1 + (unsigned)ks * 64u) ^ aswz)); \
            _Pragma("unroll")                                                 \
            for (int gi = 0; gi < 2; ++gi) {                                  \
                mfma_ab(acc[0][gi], a0, wfhh[gi][ks]);                        \
                mfma_ab(acc[1][gi], a1, wfhh[gi][ks]);                        \
            }                                                                 \
        }                                                                     \
    } else {                                                                  \
        const float* xq = xbase + (size_t)2 * (NB * NI);                      \
        PREFETCH8(XPN, xq);                                                   \
    }                                                                         \
    _Pragma("unroll")                                                         \
    for (int m = 0; m < 2; ++m)                                               \
        _Pragma("unroll")                                                     \
        for (int gi = 0; gi < 2; ++gi) {                                      \
            const int colw = (wave * 2 + gi) * 16 + fr;                       \
            _Pragma("unroll")                                                 \
            for (int j = 0; j < 4; ++j)                                       \
                gbuf[(m * 16 + fq * 4 + j) * 133 + colw] = acc[m][gi][j];     \
        }                                                                     \
    BAR_LGKM();                                                               \
    float nm0, nm1;                                                           \
    {                                                                         \
        float nc[2], nm[2];                                                   \
        const float* gb = gbuf + r_own * 133 + cp * 2;                        \
        _Pragma("unroll")                                                     \
        for (int e = 0; e < 2; ++e) {                                         \
            const float q0 = gb[0 * 16 + e], q1 = gb[1 * 16 + e];             \
            const float q2 = gb[2 * 16 + e], q3 = gb[3 * 16 + e];             \
            const float q4 = gb[4 * 16 + e], q5 = gb[5 * 16 + e];             \
            const float q6 = gb[6 * 16 + e], q7 = gb[7 * 16 + e];             \
            const float l10 = sigm_(q0);                                      \
            const float l11 = fmaxf(q1, 0.0f);                                \
            const float l12 = sigm_(q2);                                      \
            const float l13 = fmaxf(q3, 0.0f);                                \
            const float l14 = tanh_(q4);                                      \
            const float l15 = sigm_(q5);                                      \
            const float l16 = tanh_(q6);                                      \
            const float l17 = sigm_(q7);                                      \
            const float l20 = tanh_(l10 * l11);                               \
            const float l21 = tanh_(l12 + l13);                               \
            const float l22 = tanh_(l14 * l15);                               \
            const float l23 = sigm_(l16 + l17);                               \
            const float cold = (e == 0) ? cA : cB;                            \
            const float l20v = tanh_(l20 + cold);                             \
            const float ncv  = l20v * l21;                                    \
            const float l31  = tanh_(l22 + l23);                              \
            nc[e] = ncv;                                                      \
            nm[e] = tanh_(ncv * l31);                                         \
        }                                                                     \
        cA = nc[0]; cB = nc[1];                                               \
        nm0 = nm[0]; nm1 = nm[1];                                             \
    }                                                                         \
    if (st == SEQ - 1) {                                                      \
        const int obase = (g * 32 + r_own) * NH + c0 + cp * 2;                \
        out[obase + 0] = cA + nm0;                                            \
        out[obase + 1] = cB + nm1;                                            \
    } else {                                                                  \
        /* fire-and-forget tagged publish: bit14 = ((st+1)>>1)&1, |m|<1 so   */\
        /* bit14 of a real bf16 is always 0 — tag is collision-free.         */\
        const u32 tb = ((u32)(st + 1) & 2u) << 13;                            \
        u32* mw = mex + (size_t)(((st + 1) & 1) * 2 + g) * 4096               \
                      + (size_t)(r_own * 128 + role * 8 + cp);                \
        const u32 pk = ((u32)f2bf(nm0) | tb)                                  \
                     | ((((u32)f2bf(nm1)) | tb) << 16);                       \
        st_mall_u32(mw, pk);                                                  \
        {                                                                     \
            u32 w[16];                                                        \
            _Pragma("unroll")                                                 \
            for (int jj = 0; jj < 16; ++jj) {                                 \
                const float a = XPC[jj >> 1][(jj & 1) * 2 + 0];               \
                const float b = XPC[jj >> 1][(jj & 1) * 2 + 1];               \
                w[jj] = (u32)f2bf(a) | ((u32)f2bf(b) << 16);                  \
            }                                                                 \
            _Pragma("unroll")                                                 \
            for (int q = 0; q < 4; ++q) {                                     \
                u32x4 W = {w[q * 4 + 0], w[q * 4 + 1], w[q * 4 + 2], w[q * 4 + 3]}; \
                *(u32x4*)(xbuf + ((sbase + (unsigned)q * 16u) ^ sswz)) = W;   \
            }                                                                 \
        }                                                                     \
        BAR_LGKM();                                                           \
        _Pragma("unroll")                                                     \
        for (int m = 0; m < 2; ++m)                                           \
            _Pragma("unroll")                                                 \
            for (int gi = 0; gi < 2; ++gi) accx[m][gi] = fzero;               \
        _Pragma("unroll")                                                     \
        for (int ks = 0; ks < 8; ++ks) {                                      \
            bf16x8 a0 = *(const bf16x8*)(xbuf + ((ab0 + (unsigned)ks * 64u) ^ aswz)); \
            bf16x8 a1 = *(const bf16x8*)(xbuf + ((ab1 + (unsigned)ks * 64u) ^ aswz)); \
            _Pragma("unroll")                                                 \
            for (int gi = 0; gi < 2; ++gi) {                                  \
                mfma_ab(accx[0][gi], a0, wfih[gi][ks]);                       \
                mfma_ab(accx[1][gi], a1, wfih[gi][ks]);                       \
            }                                                                 \
        }                                                                     \
    }                                                                         \
} while (0)

    for (int sb = 0; sb < SEQ; sb += 2) {
        STEP(sb,     xpA, xpB);
        STEP(sb + 1, xpB, xpA);
    }
#undef STEP
}

// Per-launch re-init: parity-0 buffer -> bit14=0 words, parity-1 -> bit14=1
// words, so the first poll of each buffer mismatches its expected tag.
__global__ void nas_init(u32* ctl, u32* mex) {
    const int b = blockIdx.x, t = threadIdx.x;
    if (b < 16) {
        const u32 v = (b < 8) ? 0u : 0x40004000u;
        u32x4 vv = {v, v, v, v};
        u32* p = mex + (size_t)b * 1024 + (size_t)t * 4;
        asm volatile("global_store_dwordx4 %0, %1, off sc0 sc1" :: "v"(p), "v"(vv) : "memory");
    } else if (t < 16) {
        u32* p = ctl + t;
        asm volatile("global_store_dword %0, %1, off sc0 sc1" :: "v"(p), "v"(0u) : "memory");
    }
}

extern "C" void kernel_launch(void* const* d_in, const int* in_sizes, int n_in,
                              void* d_out, int out_size, void* d_ws, size_t ws_size,
                              hipStream_t stream) {
    (void)in_sizes; (void)n_in; (void)out_size; (void)ws_size;
    const float* x   = (const float*)d_in[0];
    const float* wih = (const float*)d_in[1];
    const float* whh = (const float*)d_in[2];
    float* out = (float*)d_out;

    u32* ctl = (u32*)d_ws;                    // claim vars
    u32* mex = (u32*)((char*)d_ws + 4096);    // 64 KB tagged m exchange

    nas_init<<<dim3(17), dim3(256), 0, stream>>>(ctl, mex);
    nas_scan<<<dim3(256), dim3(256), 0, stream>>>(x, wih, whh, out, ctl, mex);
}